// Round 5
// baseline (1397.194 us; speedup 1.0000x reference)
//
#include <hip/hip_runtime.h>
#include <hip/hip_bf16.h>

// Problem constants (fixed by the reference):
// B=16, S=40, P=512, L=48, SEQ=2048, H=1024
#define CB   16
#define CS   40
#define CP   512
#define CL   48
#define CSEQ 2048
#define CH   1024
#define H4   (CH / 4)        // 256 float4 per row
#define NSENT (CB * CS)      // 640 gather units
#define NPAIR (CB * CP)      // 8192 cls units
#define NBLK  1280           // cooperative grid (5 blocks/CU, co-resident)

typedef float fvec4 __attribute__((ext_vector_type(4)));

// ---------------------------------------------------------------------------
// One cooperative kernel.
// Phase 1 (blocks 0..639): gather sentence bs = blockIdx.x
//   - in-wave prefix scan of sentence_length -> tok, start (no setup kernel)
//   - 256 threads x 48 t-rows, register column-sum -> sent_sum
//   - __threadfence + agent-scope release add on done[b]  (G16 compliant)
// Phase 2 (all 1280 blocks): 6-7 cls pairs each; spin (agent-acquire +
//   s_sleep) until done[b]==40 for the pair's batch, then compute.
//   Co-residency is guaranteed by hipLaunchCooperativeKernel, so the spin
//   cannot deadlock. Early batches' cls overlaps late gather blocks.
// ---------------------------------------------------------------------------
__global__ void __launch_bounds__(256)
fused_kernel(const float* __restrict__ top_rep,
             const int* __restrict__ sentence_length,
             const int* __restrict__ passage_length,
             const int* __restrict__ pairs_list,
             const int* __restrict__ pairs_num,
             float* __restrict__ sen_emb,
             float* __restrict__ cls,
             float* __restrict__ sent_sum,
             int* __restrict__ done) {
    const int k    = blockIdx.x;
    const int h4   = threadIdx.x;        // float4 column 0..255
    const int lane = threadIdx.x & 63;

    // ---------------- Phase 1: sentence gather ----------------
    if (k < NSENT) {
        const int bs = k;
        const int b  = bs / CS;
        const int s  = bs - b * CS;

        // tok[s'] = (s' < pl) ? sl[b,s']-1 : 0 ; start = 1 + excl_cumsum(tok)
        const int pl = passage_length[b];
        int tokl = 0;
        if (lane < CS && lane < pl) tokl = sentence_length[b * CS + lane] - 1;
        int x = tokl;
        #pragma unroll
        for (int off = 1; off < 64; off <<= 1) {
            int y = __shfl_up(x, off);
            if (lane >= off) x += y;
        }
        const int tok   = __shfl(tokl, s);
        const int start = 1 + __shfl(x, s) - tok;

        const fvec4* __restrict__ rep =
            reinterpret_cast<const fvec4*>(top_rep) + (size_t)b * CSEQ * H4;
        fvec4* __restrict__ out =
            reinterpret_cast<fvec4*>(sen_emb) + (size_t)bs * CL * H4;

        fvec4 acc = {0.f, 0.f, 0.f, 0.f};

        #pragma unroll 8
        for (int t = 0; t < CL; ++t) {
            fvec4 v = {0.f, 0.f, 0.f, 0.f};
            if (t < tok) {
                int row = start + t;               // valid rows are in-range;
                row = min(max(row, 0), CSEQ - 1);  // clamp for safety
                v = rep[(size_t)row * H4 + h4];
            }
            __builtin_nontemporal_store(v, &out[(size_t)t * H4 + h4]);
            acc += v;
        }

        // sent_sum stays cached (normal store) for phase-2 readers
        reinterpret_cast<fvec4*>(sent_sum)[(size_t)bs * H4 + h4] = acc;

        __threadfence();          // device-scope: publish sen_emb/sent_sum
        __syncthreads();          // all threads' stores done before signal
        if (threadIdx.x == 0)
            __hip_atomic_fetch_add(&done[b], 1, __ATOMIC_RELEASE,
                                   __HIP_MEMORY_SCOPE_AGENT);
    }

    // ---------------- Phase 2: cls pairs ----------------
    // Remap so phase-1-idle blocks (640..1279) take the 7th round.
    const int pk = (k + NSENT) % NBLK;
    int ready_b = -1;

    #pragma unroll 1
    for (int r = 0; r < 7; ++r) {
        const int j = pk + NBLK * r;
        if (j >= NPAIR) break;
        const int b = j >> 9;            // j / CP
        const int i = j & (CP - 1);

        if (b != ready_b) {
            while (__hip_atomic_load(&done[b], __ATOMIC_ACQUIRE,
                                     __HIP_MEMORY_SCOPE_AGENT) < CS)
                __builtin_amdgcn_s_sleep(8);
            ready_b = b;
        }

        fvec4 rr = {0.f, 0.f, 0.f, 0.f};
        if (i < pairs_num[b]) {
            int p0 = pairs_list[(size_t)j * 2 + 0];
            int p1 = pairs_list[(size_t)j * 2 + 1];
            p0 = min(max(p0, 0), CS - 1);
            p1 = min(max(p1, 0), CS - 1);

            const int pl = passage_length[b];
            const float c0 = (p0 < pl) ? (float)(sentence_length[b * CS + p0] - 1) : 0.f;
            const float c1 = (p1 < pl) ? (float)(sentence_length[b * CS + p1] - 1) : 0.f;
            const float denom = fmaxf(c0 + c1, 1.0f);

            const fvec4* __restrict__ ss = reinterpret_cast<const fvec4*>(sent_sum);
            fvec4 a0 = ss[(size_t)(b * CS + p0) * H4 + h4];
            fvec4 a1 = ss[(size_t)(b * CS + p1) * H4 + h4];
            rr = (a0 + a1) / denom;
        }

        __builtin_nontemporal_store(
            rr, &reinterpret_cast<fvec4*>(cls)[(size_t)j * H4 + h4]);
    }
}

// ---------------------------------------------------------------------------
// Launch
// ---------------------------------------------------------------------------
extern "C" void kernel_launch(void* const* d_in, const int* in_sizes, int n_in,
                              void* d_out, int out_size, void* d_ws, size_t ws_size,
                              hipStream_t stream) {
    const int*   sentence_length = (const int*)  d_in[0];   // (B,S)
    const int*   pairs_list      = (const int*)  d_in[1];   // (B,P,2)
    const int*   passage_length  = (const int*)  d_in[2];   // (B,)
    const int*   pairs_num       = (const int*)  d_in[3];   // (B,)
    // d_in[4] = max_sentence_length scalar (compile-time CL here)
    const float* top_rep         = (const float*)d_in[5];   // (B,SEQ,H)

    float* out     = (float*)d_out;
    float* sen_emb = out;                                   // (B,S,L,H)
    float* cls     = out + (size_t)CB * CS * CL * CH;       // (B,P,1,H)

    // Workspace: sent_sum (B*S*H f32 = 2.6 MB) | done (B ints)
    float* sent_sum = (float*)d_ws;
    int*   done     = (int*)((char*)d_ws + (size_t)CB * CS * CH * sizeof(float));

    hipMemsetAsync(done, 0, CB * sizeof(int), stream);

    void* args[] = {
        (void*)&top_rep, (void*)&sentence_length, (void*)&passage_length,
        (void*)&pairs_list, (void*)&pairs_num,
        (void*)&sen_emb, (void*)&cls, (void*)&sent_sum, (void*)&done
    };
    hipLaunchCooperativeKernel((void*)fused_kernel, dim3(NBLK), dim3(256),
                               args, 0, stream);
}

// Round 6
// 206.233 us; speedup vs baseline: 6.7748x; 6.7748x over previous
//
#include <hip/hip_runtime.h>
#include <hip/hip_bf16.h>

// Problem constants (fixed by the reference):
// B=16, S=40, P=512, L=48, SEQ=2048, H=1024
#define CB   16
#define CS   40
#define CP   512
#define CL   48
#define CSEQ 2048
#define CH   1024
#define H4   (CH / 4)        // 256 float4 per row
#define NSENT (CB * CS)      // 640 gather units == grid size
#define NPAIR (CB * CP)      // 8192 cls units (12-13 per block)

typedef float fvec4 __attribute__((ext_vector_type(4)));

// ---------------------------------------------------------------------------
// One cooperative kernel, 640 blocks x 256 threads (all co-resident).
// Phase 1: block k gathers sentence bs=k (prefix-scan bookkeeping in-wave,
//   48 t-rows, register column sums -> sent_sum), then publishes via
//   __threadfence + agent-scope RELEASE fetch_add on done[b].
// Phase 2: block k processes 12-13 contiguous cls pairs (covering batch
//   ~= its own gather batch). ONLY thread 0 polls done[b] with RELAXED
//   loads + s_sleep (no per-iteration L1 invalidation storm — the R4 bug),
//   then one ACQUIRE load, then __syncthreads releases the block.
// ---------------------------------------------------------------------------
__global__ void __launch_bounds__(256)
fused_kernel(const float* __restrict__ top_rep,
             const int* __restrict__ sentence_length,
             const int* __restrict__ passage_length,
             const int* __restrict__ pairs_list,
             const int* __restrict__ pairs_num,
             float* __restrict__ sen_emb,
             float* __restrict__ cls,
             float* __restrict__ sent_sum,
             int* __restrict__ done) {
    const int k    = blockIdx.x;         // 0..639 == (b*CS + s)
    const int h4   = threadIdx.x;        // float4 column 0..255
    const int lane = threadIdx.x & 63;

    // ---------------- Phase 1: sentence gather ----------------
    {
        const int b = k / CS;
        const int s = k - b * CS;

        // tok[s'] = (s' < pl) ? sl[b,s']-1 : 0 ; start = 1 + excl_cumsum(tok)
        const int pl = passage_length[b];
        int tokl = 0;
        if (lane < CS && lane < pl) tokl = sentence_length[b * CS + lane] - 1;
        int x = tokl;
        #pragma unroll
        for (int off = 1; off < 64; off <<= 1) {
            int y = __shfl_up(x, off);
            if (lane >= off) x += y;
        }
        const int tok   = __shfl(tokl, s);
        const int start = 1 + __shfl(x, s) - tok;

        const fvec4* __restrict__ rep =
            reinterpret_cast<const fvec4*>(top_rep) + (size_t)b * CSEQ * H4;
        fvec4* __restrict__ out =
            reinterpret_cast<fvec4*>(sen_emb) + (size_t)k * CL * H4;

        fvec4 acc = {0.f, 0.f, 0.f, 0.f};

        #pragma unroll 8
        for (int t = 0; t < CL; ++t) {
            fvec4 v = {0.f, 0.f, 0.f, 0.f};
            if (t < tok) {
                int row = start + t;               // valid rows are in-range;
                row = min(max(row, 0), CSEQ - 1);  // clamp for safety
                v = rep[(size_t)row * H4 + h4];
            }
            __builtin_nontemporal_store(v, &out[(size_t)t * H4 + h4]);
            acc += v;
        }

        // sent_sum stays cached (normal store) for phase-2 readers
        reinterpret_cast<fvec4*>(sent_sum)[(size_t)k * H4 + h4] = acc;

        __threadfence();          // publish sen_emb/sent_sum device-wide
        __syncthreads();          // all threads' stores done before signal
        if (threadIdx.x == 0)
            __hip_atomic_fetch_add(&done[b], 1, __ATOMIC_RELEASE,
                                   __HIP_MEMORY_SCOPE_AGENT);
    }

    // ---------------- Phase 2: cls pairs ----------------
    // Contiguous pair ranges: blocks 0..511 get 13 pairs, 512..639 get 12.
    int j0, cnt;
    if (k < 512) { j0 = k * 13;      cnt = 13; }
    else         { j0 = 512 + k * 12; cnt = 12; }

    int ready_b = -1;

    #pragma unroll 1
    for (int r = 0; r < cnt; ++r) {
        const int j = j0 + r;
        const int b = j >> 9;            // j / CP
        const int i = j & (CP - 1);

        if (b != ready_b) {              // block-uniform condition
            if (threadIdx.x == 0) {
                // RELAXED poll (no L1-invalidating acquire per iteration)
                while (__hip_atomic_load(&done[b], __ATOMIC_RELAXED,
                                         __HIP_MEMORY_SCOPE_AGENT) < CS)
                    __builtin_amdgcn_s_sleep(2);
                // single acquire to synchronize-with the release adds
                (void)__hip_atomic_load(&done[b], __ATOMIC_ACQUIRE,
                                        __HIP_MEMORY_SCOPE_AGENT);
            }
            __syncthreads();
            ready_b = b;
        }

        fvec4 rr = {0.f, 0.f, 0.f, 0.f};
        if (i < pairs_num[b]) {
            int p0 = pairs_list[(size_t)j * 2 + 0];
            int p1 = pairs_list[(size_t)j * 2 + 1];
            p0 = min(max(p0, 0), CS - 1);
            p1 = min(max(p1, 0), CS - 1);

            const int pl = passage_length[b];
            const float c0 = (p0 < pl) ? (float)(sentence_length[b * CS + p0] - 1) : 0.f;
            const float c1 = (p1 < pl) ? (float)(sentence_length[b * CS + p1] - 1) : 0.f;
            const float denom = fmaxf(c0 + c1, 1.0f);

            const fvec4* __restrict__ ss = reinterpret_cast<const fvec4*>(sent_sum);
            fvec4 a0 = ss[(size_t)(b * CS + p0) * H4 + h4];
            fvec4 a1 = ss[(size_t)(b * CS + p1) * H4 + h4];
            rr = (a0 + a1) / denom;
        }

        __builtin_nontemporal_store(
            rr, &reinterpret_cast<fvec4*>(cls)[(size_t)j * H4 + h4]);
    }
}

// ---------------------------------------------------------------------------
// Launch
// ---------------------------------------------------------------------------
extern "C" void kernel_launch(void* const* d_in, const int* in_sizes, int n_in,
                              void* d_out, int out_size, void* d_ws, size_t ws_size,
                              hipStream_t stream) {
    const int*   sentence_length = (const int*)  d_in[0];   // (B,S)
    const int*   pairs_list      = (const int*)  d_in[1];   // (B,P,2)
    const int*   passage_length  = (const int*)  d_in[2];   // (B,)
    const int*   pairs_num       = (const int*)  d_in[3];   // (B,)
    // d_in[4] = max_sentence_length scalar (compile-time CL here)
    const float* top_rep         = (const float*)d_in[5];   // (B,SEQ,H)

    float* out     = (float*)d_out;
    float* sen_emb = out;                                   // (B,S,L,H)
    float* cls     = out + (size_t)CB * CS * CL * CH;       // (B,P,1,H)

    // Workspace: sent_sum (B*S*H f32 = 2.6 MB) | done (B ints)
    float* sent_sum = (float*)d_ws;
    int*   done     = (int*)((char*)d_ws + (size_t)CB * CS * CH * sizeof(float));

    hipMemsetAsync(done, 0, CB * sizeof(int), stream);

    void* args[] = {
        (void*)&top_rep, (void*)&sentence_length, (void*)&passage_length,
        (void*)&pairs_list, (void*)&pairs_num,
        (void*)&sen_emb, (void*)&cls, (void*)&sent_sum, (void*)&done
    };
    hipLaunchCooperativeKernel((void*)fused_kernel, dim3(NSENT), dim3(256),
                               args, 0, stream);
}

// Round 7
// 42.215 us; speedup vs baseline: 33.0973x; 4.8853x over previous
//
#include <hip/hip_runtime.h>
#include <hip/hip_bf16.h>

// Problem constants (fixed by the reference):
// B=16, S=40, P=512, L=48, SEQ=2048, H=1024
#define CB   16
#define CS   40
#define CP   512
#define CL   48
#define CSEQ 2048
#define CH   1024
#define H4   (CH / 4)        // 256 float4 per row
#define NQ   4               // H-quarters per sentence
#define NSENT (CB * CS)      // 640 sentences
#define NPAIR (CB * CP)      // 8192 cls pairs

typedef float fvec4 __attribute__((ext_vector_type(4)));

// ---------------------------------------------------------------------------
// Kernel A: gather. Block = one (sentence, H-quarter); 64 threads (1 wave).
// Thread owns one float4 column of the quarter; loops all 48 t-rows with a
// register accumulator; writes its sent_sum quarter directly (exclusive
// column ownership -> no cross-block reduction). 2560 blocks = 10/CU, so
// per-CU load imbalance (tok in [7,47]) averages over ~10 samples instead
// of 2.5 -> smaller max-over-CUs makespan tail (the R3 gap theory).
// ---------------------------------------------------------------------------
__global__ void __launch_bounds__(64)
gather_kernel(const float* __restrict__ top_rep,
              const int* __restrict__ sentence_length,
              const int* __restrict__ passage_length,
              float* __restrict__ sen_emb,
              float* __restrict__ sent_sum) {
    const int blk  = blockIdx.x;         // bs*NQ + q
    const int q    = blk & (NQ - 1);
    const int bs   = blk >> 2;
    const int b    = bs / CS;
    const int s    = bs - b * CS;
    const int lane = threadIdx.x;        // 0..63
    const int h4   = q * 64 + lane;      // float4 column 0..255

    // Per-wave prefix scan over the 40 sentences of batch b.
    // tok[s'] = (s' < pl) ? sl[b,s']-1 : 0 ; start = 1 + excl_cumsum(tok)
    const int pl = passage_length[b];
    int tokl = 0;
    if (lane < CS && lane < pl) tokl = sentence_length[b * CS + lane] - 1;
    int x = tokl;
    #pragma unroll
    for (int off = 1; off < 64; off <<= 1) {
        int y = __shfl_up(x, off);
        if (lane >= off) x += y;
    }
    const int tok   = __shfl(tokl, s);
    const int start = 1 + __shfl(x, s) - tok;

    const fvec4* __restrict__ rep =
        reinterpret_cast<const fvec4*>(top_rep) + (size_t)b * CSEQ * H4;
    fvec4* __restrict__ out =
        reinterpret_cast<fvec4*>(sen_emb) + (size_t)bs * CL * H4;

    fvec4 acc = {0.f, 0.f, 0.f, 0.f};

    #pragma unroll 8
    for (int t = 0; t < CL; ++t) {
        fvec4 v = {0.f, 0.f, 0.f, 0.f};
        if (t < tok) {
            int row = start + t;               // valid rows are in-range;
            row = min(max(row, 0), CSEQ - 1);  // clamp for safety
            v = rep[(size_t)row * H4 + h4];
        }
        __builtin_nontemporal_store(v, &out[(size_t)t * H4 + h4]);
        acc += v;
    }

    // Exclusive column -> direct store of this quarter of sent_sum.
    reinterpret_cast<fvec4*>(sent_sum)[(size_t)bs * H4 + h4] = acc;
}

// ---------------------------------------------------------------------------
// Kernel B: cls = masked (sent_sum[p0] + sent_sum[p1]) / max(c0+c1, 1)
// Counts derived directly from sentence_length/passage_length.
// ---------------------------------------------------------------------------
__global__ void __launch_bounds__(256)
cls_kernel(const int* __restrict__ pairs_list,
           const int* __restrict__ pairs_num,
           const int* __restrict__ sentence_length,
           const int* __restrict__ passage_length,
           const float* __restrict__ sent_sum,
           float* __restrict__ cls) {
    const int blk = blockIdx.x;              // b*CP + i
    const int b   = blk >> 9;
    const int i   = blk & (CP - 1);
    const int h4  = threadIdx.x;

    fvec4 r = {0.f, 0.f, 0.f, 0.f};

    if (i < pairs_num[b]) {
        int p0 = pairs_list[(size_t)blk * 2 + 0];
        int p1 = pairs_list[(size_t)blk * 2 + 1];
        p0 = min(max(p0, 0), CS - 1);
        p1 = min(max(p1, 0), CS - 1);

        const int pl = passage_length[b];
        const float c0 = (p0 < pl) ? (float)(sentence_length[b * CS + p0] - 1) : 0.f;
        const float c1 = (p1 < pl) ? (float)(sentence_length[b * CS + p1] - 1) : 0.f;
        const float denom = fmaxf(c0 + c1, 1.0f);

        const fvec4* __restrict__ ss = reinterpret_cast<const fvec4*>(sent_sum);
        fvec4 a0 = ss[(size_t)(b * CS + p0) * H4 + h4];
        fvec4 a1 = ss[(size_t)(b * CS + p1) * H4 + h4];
        r = (a0 + a1) / denom;
    }

    __builtin_nontemporal_store(
        r, &reinterpret_cast<fvec4*>(cls)[(size_t)blk * H4 + h4]);
}

// ---------------------------------------------------------------------------
// Launch
// ---------------------------------------------------------------------------
extern "C" void kernel_launch(void* const* d_in, const int* in_sizes, int n_in,
                              void* d_out, int out_size, void* d_ws, size_t ws_size,
                              hipStream_t stream) {
    const int*   sentence_length = (const int*)  d_in[0];   // (B,S)
    const int*   pairs_list      = (const int*)  d_in[1];   // (B,P,2)
    const int*   passage_length  = (const int*)  d_in[2];   // (B,)
    const int*   pairs_num       = (const int*)  d_in[3];   // (B,)
    // d_in[4] = max_sentence_length scalar (compile-time CL here)
    const float* top_rep         = (const float*)d_in[5];   // (B,SEQ,H)

    float* out     = (float*)d_out;
    float* sen_emb = out;                                   // (B,S,L,H)
    float* cls     = out + (size_t)CB * CS * CL * CH;       // (B,P,1,H)

    // Workspace: sent_sum (B*S*H f32 = 2.6 MB)
    float* sent_sum = (float*)d_ws;

    gather_kernel<<<NSENT * NQ, 64, 0, stream>>>(
        top_rep, sentence_length, passage_length, sen_emb, sent_sum);

    cls_kernel<<<NPAIR, 256, 0, stream>>>(
        pairs_list, pairs_num, sentence_length, passage_length, sent_sum, cls);
}